// Round 12
// baseline (112.549 us; speedup 1.0000x reference)
//
#include <hip/hip_runtime.h>
#include <hip/hip_bf16.h>

typedef __attribute__((ext_vector_type(8))) __bf16 bf16x8;
typedef __attribute__((ext_vector_type(4))) float f32x4;
typedef __attribute__((ext_vector_type(16))) float f32x16;

#if __has_builtin(__builtin_amdgcn_exp2f)
#define EXP2F(x) __builtin_amdgcn_exp2f(x)
#else
#define EXP2F(x) exp2f(x)
#endif

static constexpr int BB = 8, CC = 64, NN = 4096;
// ws layout (bytes): qfrag[2MB] | kfrag[2MB @2MB] | vfrag[4MB @4MB]
static constexpr size_t QF_OFF = 0;
static constexpr size_t KF_OFF = (size_t)2 << 20;
static constexpr size_t VF_OFF = (size_t)4 << 20;

// 16x16x32 fragment arrays (bf16) — the R6-measured-best attn layouts:
//  qfrag[b][itile(256)][lane][8] : i = itile*16 + (lane&15); qd=lane>>4
//      sections: qd0=qhi, qd1=qlo, qd2=qhi, qd3=qlo (q pre-scaled log2e, +bias)
//  kfrag[b][jt(128)][th(2)][lane][8] : j = jt*32 + th*16 + (lane&15)
//      sections: qd0=khi, qd1=khi, qd2=klo, qd3=klo (+bias)
//  -> energy = (khi+klo)*(qhi+qlo) exact over the bf16 pairs
//  vfrag[b][jt(128)][ct(4)][lane][8] : c = ct*16 + (lane&15); slot r:
//      r<4 -> V[c][jt*32 + 4*qd + r], r>=4 -> V[c][jt*32 + 16 + 4*qd + (r&3)]
//  (jperm matches energy C/D layout: exp() feeds PV B-operand directly)

// proj R12: identical compute to R11 (MFMA projections), but block->work
// mapping now b = blk & 7 (same as attn). ROUND-12 THEORY: with the old
// b = blk>>6 mapping, batch-b frags were WRITTEN from blocks on all 8 XCDs
// (round-robin dispatch), scattering them across all 8 L2s; attn's batch-b
// readers (pinned to XCD b) then pulled 7/8 of 393 MB cross-die (~33 us ~=
// attn's measured 34). Matching producer and consumer XCD makes the 1 MB
// per-batch frag set local-L2-resident.
__global__ __launch_bounds__(256, 2) void proj_kernel(
    const float* __restrict__ query, const float* __restrict__ value,
    const float* __restrict__ Wq, const float* __restrict__ bq,
    const float* __restrict__ Wk, const float* __restrict__ bk,
    const float* __restrict__ Wv, const float* __restrict__ bv,
    char* __restrict__ ws) {
  __shared__ float xqs[64][68];     // query tile [c][px], stride 68 (16B-aligned rows)
  __shared__ float xvs[64][68];     // value tile [c][px]
  __shared__ __bf16 vlds[64][66];   // [px][c] bf16
  __shared__ float  qlds[64][9];    // [px][o], log2e-scaled, +bias
  __shared__ float  klds[64][9];
  const float LOG2E = 1.4426950408889634f;
  int t = threadIdx.x;
  int blk = blockIdx.x;
  int b = blk & 7;                  // XCD-batch affinity (matches attn)
  int pxg = blk >> 3;               // 0..63 pixel-group
  int px0 = pxg << 6;               // 64 px per block

  {  // cooperative input stage: thread t -> channel t>>2, 16-px segment, 4x float4
    int c = t >> 2, seg = (t & 3) << 4;
    size_t gaddr = (size_t)b * CC * NN + (size_t)c * NN + px0 + seg;
    #pragma unroll
    for (int qq = 0; qq < 4; ++qq) {
      *(float4*)&xqs[c][seg + 4 * qq] = *(const float4*)(query + gaddr + 4 * qq);
      *(float4*)&xvs[c][seg + 4 * qq] = *(const float4*)(value + gaddr + 4 * qq);
    }
  }
  __syncthreads();

  int lane = t & 63, m = lane & 31, hA = lane >> 5;
  int w = t >> 6;                   // 4 waves
  int tile = w & 1, role = w >> 1;  // tile: which 32-px half; role: V vs QK
  int pxl = tile * 32 + m;

  f32x16 Z16;
  #pragma unroll
  for (int r = 0; r < 16; ++r) Z16[r] = 0.f;

  if (role == 0) {
    // ---- V-projection: D[c][px] = Wv·value, two 32-c tiles
    bf16x8 A[2][4];
    #pragma unroll
    for (int ct = 0; ct < 2; ++ct)
      #pragma unroll
      for (int kb = 0; kb < 4; ++kb) {
        const float* wb = Wv + (ct * 32 + m) * 64 + kb * 16 + hA * 8;
        #pragma unroll
        for (int r = 0; r < 8; ++r) A[ct][kb][r] = (__bf16)wb[r];
      }
    f32x16 acc0 = Z16, acc1 = Z16;
    #pragma unroll
    for (int kb = 0; kb < 4; ++kb) {
      bf16x8 Bv;
      #pragma unroll
      for (int r = 0; r < 8; ++r) Bv[r] = (__bf16)xvs[kb * 16 + hA * 8 + r][pxl];
      acc0 = __builtin_amdgcn_mfma_f32_32x32x16_bf16(A[0][kb], Bv, acc0, 0, 0, 0);
      acc1 = __builtin_amdgcn_mfma_f32_32x32x16_bf16(A[1][kb], Bv, acc1, 0, 0, 0);
    }
    #pragma unroll
    for (int reg = 0; reg < 16; ++reg) {
      int crow = (reg & 3) + 8 * (reg >> 2) + 4 * hA;
      vlds[pxl][crow]      = (__bf16)(acc0[reg] + bv[crow]);
      vlds[pxl][crow + 32] = (__bf16)(acc1[reg] + bv[crow + 32]);
    }
  } else {
    // ---- QK projection, hi/lo exact (missing term Wlo·xlo ~ 3e-5)
    bf16x8 A[4];
    int r8 = m & 7;
    bool isk = (m >> 3) & 1;                      // rows 8-15 / 24-31 -> Wk
    const float* wrow = (isk ? Wk : Wq) + r8 * 64;
    float scale = isk ? 1.0f : LOG2E;             // fold log2e into Wq
    #pragma unroll
    for (int kb = 0; kb < 4; ++kb) {
      #pragma unroll
      for (int r = 0; r < 8; ++r) {
        float v = wrow[kb * 16 + hA * 8 + r] * scale;
        __bf16 hi = (__bf16)v;
        A[kb][r] = (m < 16) ? hi : (__bf16)(v - (float)hi);
      }
    }
    f32x16 accH = Z16, accL = Z16;
    #pragma unroll
    for (int kb = 0; kb < 4; ++kb) {
      bf16x8 Bh, Bl;
      #pragma unroll
      for (int r = 0; r < 8; ++r) {
        float x = xqs[kb * 16 + hA * 8 + r][pxl];
        __bf16 h = (__bf16)x;
        Bh[r] = h;
        Bl[r] = (__bf16)(x - (float)h);
      }
      accH = __builtin_amdgcn_mfma_f32_32x32x16_bf16(A[kb], Bh, accH, 0, 0, 0);
      accL = __builtin_amdgcn_mfma_f32_32x32x16_bf16(A[kb], Bl, accL, 0, 0, 0);
    }
    // rows o and o+16 sit in the same lane: regs j and 8+j
    #pragma unroll
    for (int j = 0; j < 4; ++j) {
      int o = 4 * hA + j;
      qlds[pxl][o] = accH[j] + accH[8 + j] + accL[j] + bq[o] * LOG2E;
      klds[pxl][o] = accH[4 + j] + accH[12 + j] + accL[4 + j] + bk[o];
    }
  }
  __syncthreads();

  // ---- fragment building (16x16 layouts; 4-wave split)
  __bf16* qfrag = (__bf16*)(ws + QF_OFF);
  __bf16* kfrag = (__bf16*)(ws + KF_OFF);
  __bf16* vfrag = (__bf16*)(ws + VF_OFF);
  int l = lane, cp = l & 15, qd = l >> 4;

  #pragma unroll
  for (int ci = 0; ci < 2; ++ci) {  // vfrag: wave w -> jt = w>>1, ct = 2*(w&1)+ci
    int jt = w >> 1, ct = (w & 1) * 2 + ci;
    bf16x8 v8;
    #pragma unroll
    for (int r = 0; r < 8; ++r) {
      int jj = (r < 4) ? (4 * qd + r) : (16 + 4 * qd + (r & 3));
      v8[r] = vlds[jt * 32 + jj][ct * 16 + cp];
    }
    int jtg = pxg * 2 + jt;
    *(bf16x8*)(vfrag + ((((size_t)b * 128 + jtg) * 4 + ct) * 64 + l) * 8) = v8;
  }
  {  // kfrag: jt = w>>1, th = w&1
    int jt = w >> 1, th = w & 1;
    int pxk = jt * 32 + th * 16 + cp;
    bf16x8 k8;
    #pragma unroll
    for (int r = 0; r < 8; ++r) {
      float kv = klds[pxk][r];
      __bf16 hi = (__bf16)kv;
      __bf16 lo = (__bf16)(kv - (float)hi);
      k8[r] = (qd < 2) ? hi : lo;
    }
    int jtg = pxg * 2 + jt;
    *(bf16x8*)(kfrag + ((((size_t)b * 128 + jtg) * 2 + th) * 64 + l) * 8) = k8;
  }
  {  // qfrag: it = w
    int il = w * 16 + cp;
    bf16x8 q8;
    #pragma unroll
    for (int r = 0; r < 8; ++r) {
      float qv = qlds[il][r];
      __bf16 hi = (__bf16)qv;
      __bf16 lo = (__bf16)(qv - (float)hi);
      q8[r] = ((qd & 1) == 0) ? hi : lo;
    }
    int itg = pxg * 4 + w;
    *(bf16x8*)(qfrag + (((size_t)b * 256 + itg) * 64 + l) * 8) = q8;
  }
}

// attn: the R6-measured-best structure (~34 us). 64 i-rows/block, 4 waves
// each take a j-quarter, acc[4][4] (64 AGPR, no spill at (256,2)),
// even/odd register prefetch, XCD-batch affinity b = blk&7.
__global__ __launch_bounds__(256, 2) void attn_kernel(
    const char* __restrict__ ws, const float* __restrict__ value,
    float* __restrict__ out) {
  __shared__ float lds_acc[32 * 4 * 64];  // [elem(32)][wave(4)][lane] 32KB
  __shared__ float lds_l[16 * 64];        // [(it*4+w)][lane]
  const __bf16* qfrag = (const __bf16*)(ws + QF_OFF);
  const __bf16* kfrag = (const __bf16*)(ws + KF_OFF);
  const __bf16* vfrag = (const __bf16*)(ws + VF_OFF);
  int tid = threadIdx.x;
  int w = tid >> 6, lane = tid & 63;
  int blk = blockIdx.x;            // 512 blocks
  int b = blk & 7;                 // XCD affinity
  int slot = blk >> 3;             // 0..63
  int i0 = slot << 6;
  int itg0 = slot * 4;

  bf16x8 qf[4];
  #pragma unroll
  for (int it = 0; it < 4; ++it)
    qf[it] = *(const bf16x8*)(qfrag + (((size_t)b * 256 + itg0 + it) * 64 + lane) * 8);

  f32x4 acc[4][4];
  #pragma unroll
  for (int ct = 0; ct < 4; ++ct)
    #pragma unroll
    for (int it = 0; it < 4; ++it) acc[ct][it] = (f32x4){0.f, 0.f, 0.f, 0.f};
  float lsum[4] = {0.f, 0.f, 0.f, 0.f};

  const __bf16* kb = kfrag + (((size_t)b * 128 + w * 32) * 2 * 64 + lane) * 8;
  const __bf16* vb = vfrag + (((size_t)b * 128 + w * 32) * 4 * 64 + lane) * 8;

  auto compute = [&](bf16x8 kf0, bf16x8 kf1, bf16x8 vf0, bf16x8 vf1,
                     bf16x8 vf2, bf16x8 vf3) {
    const f32x4 z = (f32x4){0.f, 0.f, 0.f, 0.f};
    #pragma unroll
    for (int it = 0; it < 4; ++it) {
      f32x4 e0 = __builtin_amdgcn_mfma_f32_16x16x32_bf16(kf0, qf[it], z, 0, 0, 0);
      f32x4 e1 = __builtin_amdgcn_mfma_f32_16x16x32_bf16(kf1, qf[it], z, 0, 0, 0);
      bf16x8 pf;
      #pragma unroll
      for (int g = 0; g < 4; ++g) {
        float p0 = EXP2F(e0[g]); lsum[it] += p0; pf[g] = (__bf16)p0;
        float p1 = EXP2F(e1[g]); lsum[it] += p1; pf[4 + g] = (__bf16)p1;
      }
      acc[0][it] = __builtin_amdgcn_mfma_f32_16x16x32_bf16(vf0, pf, acc[0][it], 0, 0, 0);
      acc[1][it] = __builtin_amdgcn_mfma_f32_16x16x32_bf16(vf1, pf, acc[1][it], 0, 0, 0);
      acc[2][it] = __builtin_amdgcn_mfma_f32_16x16x32_bf16(vf2, pf, acc[2][it], 0, 0, 0);
      acc[3][it] = __builtin_amdgcn_mfma_f32_16x16x32_bf16(vf3, pf, acc[3][it], 0, 0, 0);
    }
  };

  // prefetch itx=0
  bf16x8 k0a = *(const bf16x8*)(kb);
  bf16x8 k1a = *(const bf16x8*)(kb + 512);
  bf16x8 v0a = *(const bf16x8*)(vb);
  bf16x8 v1a = *(const bf16x8*)(vb + 512);
  bf16x8 v2a = *(const bf16x8*)(vb + 1024);
  bf16x8 v3a = *(const bf16x8*)(vb + 1536);

  #pragma unroll 1
  for (int itx = 0; itx < 16; ++itx) {
    kb += 1024; vb += 2048;
    bf16x8 k0b = *(const bf16x8*)(kb);
    bf16x8 k1b = *(const bf16x8*)(kb + 512);
    bf16x8 v0b = *(const bf16x8*)(vb);
    bf16x8 v1b = *(const bf16x8*)(vb + 512);
    bf16x8 v2b = *(const bf16x8*)(vb + 1024);
    bf16x8 v3b = *(const bf16x8*)(vb + 1536);
    compute(k0a, k1a, v0a, v1a, v2a, v3a);
    kb += 1024; vb += 2048;
    // last prefetch overshoots into adjacent ws region - harmless, unused
    k0a = *(const bf16x8*)(kb);
    k1a = *(const bf16x8*)(kb + 512);
    v0a = *(const bf16x8*)(vb);
    v1a = *(const bf16x8*)(vb + 512);
    v2a = *(const bf16x8*)(vb + 1024);
    v3a = *(const bf16x8*)(vb + 1536);
    compute(k0b, k1b, v0b, v1b, v2b, v3b);
  }

  #pragma unroll
  for (int it = 0; it < 4; ++it) {
    lsum[it] += __shfl_xor(lsum[it], 16, 64);
    lsum[it] += __shfl_xor(lsum[it], 32, 64);
    lds_l[(it * 4 + w) * 64 + lane] = lsum[it];
  }

  int ect = tid >> 6, l = tid & 63;
  #pragma unroll
  for (int p = 0; p < 2; ++p) {
    if (p) __syncthreads();   // protect lds_acc from overwrite before reads done
    #pragma unroll
    for (int ct = 0; ct < 4; ++ct)
      #pragma unroll
      for (int itl = 0; itl < 2; ++itl)
        #pragma unroll
        for (int r = 0; r < 4; ++r) {
          int e = ct * 8 + itl * 4 + r;
          lds_acc[(e * 4 + w) * 64 + lane] = acc[ct][2 * p + itl][r];
        }
    __syncthreads();
    #pragma unroll
    for (int itl = 0; itl < 2; ++itl) {
      int it = 2 * p + itl;
      float ls = 0.f;
      #pragma unroll
      for (int ww = 0; ww < 4; ++ww) ls += lds_l[(it * 4 + ww) * 64 + (l & 15)];
      float inv = 1.0f / ls;
      int n = i0 + it * 16 + (l & 15);
      #pragma unroll
      for (int r = 0; r < 4; ++r) {
        int e = ect * 8 + itl * 4 + r;
        float s = 0.f;
        #pragma unroll
        for (int ww = 0; ww < 4; ++ww) s += lds_acc[(e * 4 + ww) * 64 + l];
        int c = ect * 16 + (l >> 4) * 4 + r;
        size_t idx = ((size_t)b * CC + c) * NN + n;
        out[idx] = s * inv + value[idx];
      }
    }
  }
}

extern "C" void kernel_launch(void* const* d_in, const int* in_sizes, int n_in,
                              void* d_out, int out_size, void* d_ws, size_t ws_size,
                              hipStream_t stream) {
  const float* query = (const float*)d_in[0];
  const float* value = (const float*)d_in[1];
  const float* Wq = (const float*)d_in[2];
  const float* bq = (const float*)d_in[3];
  const float* Wk = (const float*)d_in[4];
  const float* bk = (const float*)d_in[5];
  const float* Wv = (const float*)d_in[6];
  const float* bv = (const float*)d_in[7];
  float* out = (float*)d_out;

  proj_kernel<<<512, 256, 0, stream>>>(query, value, Wq, bq, Wk, bk, Wv, bv, (char*)d_ws);
  attn_kernel<<<512, 256, 0, stream>>>((const char*)d_ws, value, out);
}